// Round 7
// baseline (364.229 us; speedup 1.0000x reference)
//
#include <hip/hip_runtime.h>

// xLSTMCell, round 7. B=4096, D_IN=H=1024, 6 gates, fp32 in/out.
//   (K1) cvt x,h,W,U fp32->bf16 into ws
//   (K2) gemm_z v2: M=4096 N=6144 K=2048 -> 7 bf16 z-planes.
//        A-fragments loaded DIRECT global->VGPR (no LDS round-trip; L1 absorbs
//        the 2x intra-block reuse). Only B staged via global_load_lds(16B)+XOR
//        swizzle. LDS traffic/block-k0: 96 KB -> 48 KB; ceiling 41% -> 83% Mfma.
//   (K3) combine: elementwise gates -> h_new, c_new
// Fallbacks: R5 fused kernel (ws >= 40 MB), R2 fp32-staging kernel (else).

#define B_DIM 4096
#define K_DIM 1024
#define H_DIM 1024

using f32x4  = __attribute__((ext_vector_type(4))) float;
using bf16x8 = __attribute__((ext_vector_type(8))) __bf16;
using u16x4  = __attribute__((ext_vector_type(4))) unsigned short;
using u16x8  = __attribute__((ext_vector_type(8))) unsigned short;

__device__ __forceinline__ unsigned short f2bf(float f) {
    union { float f; unsigned int i; } v; v.f = f;
    unsigned int r = v.i + 0x7fffu + ((v.i >> 16) & 1u);  // RNE
    return (unsigned short)(r >> 16);
}
__device__ __forceinline__ float bf2f(unsigned short u) {
    union { unsigned int i; float f; } v; v.i = ((unsigned int)u) << 16; return v.f;
}
__device__ __forceinline__ float sigm(float x) { return 1.f / (1.f + __expf(-x)); }
__device__ __forceinline__ float tanh_fast(float x) {
    float ax = fminf(fabsf(x), 15.f);
    float e  = __expf(2.f * ax);
    float t  = (e - 1.f) / (e + 1.f);
    return copysignf(t, x);
}

#define GLDS(gp, lp) __builtin_amdgcn_global_load_lds(                          \
        (const __attribute__((address_space(1))) void*)(gp),                    \
        (__attribute__((address_space(3))) void*)(lp), 16, 0, 0)

// ws layout (u16 elems)
constexpr size_t WS_X = 0, WS_H = 4194304, WS_W = 8388608, WS_U = 14680064;
constexpr size_t WS_Z = 20971520;
constexpr size_t ZPL  = 4194304;

// ---------------------------------------------------------------- convert ---
__global__ __launch_bounds__(256) void cvt_all(const float* __restrict__ x,
                                               const float* __restrict__ h,
                                               const float* __restrict__ W,
                                               const float* __restrict__ U,
                                               unsigned short* __restrict__ ws)
{
    const int b = blockIdx.x;
    const float* src; unsigned short* dst; size_t base;
    if      (b < 512)  { src = x; dst = ws + WS_X; base = (size_t)b          * 8192; }
    else if (b < 1024) { src = h; dst = ws + WS_H; base = (size_t)(b - 512)  * 8192; }
    else if (b < 1792) { src = W; dst = ws + WS_W; base = (size_t)(b - 1024) * 8192; }
    else               { src = U; dst = ws + WS_U; base = (size_t)(b - 1792) * 8192; }
#pragma unroll
    for (int k = 0; k < 4; ++k) {
        size_t f = base + ((size_t)k * 256 + threadIdx.x) * 8;
        f32x4 v0 = *(const f32x4*)&src[f];
        f32x4 v1 = *(const f32x4*)&src[f + 4];
        u16x8 p = { f2bf(v0[0]), f2bf(v0[1]), f2bf(v0[2]), f2bf(v0[3]),
                    f2bf(v1[0]), f2bf(v1[1]), f2bf(v1[2]), f2bf(v1[3]) };
        *(u16x8*)&dst[f] = p;
    }
}

// ------------------------------------------------------------------ gemm_z ---
// grid (48, 32): nt -> gate g = nt>>3, hcol0 = (nt&7)*128; mt -> m-band.
// 256 thr, 4 waves 2x2, wave tile 64x64. A direct-from-global, B via LDS.
__global__ __launch_bounds__(256, 3)
void gemm_z(const unsigned short* __restrict__ xb,
            const unsigned short* __restrict__ hb,
            const unsigned short* __restrict__ Wb,
            const unsigned short* __restrict__ Ub,
            const float* __restrict__ b_all,
            unsigned short* __restrict__ z)
{
    __shared__ unsigned short lB[128 * 64];   // 16 KB

    const int tid  = threadIdx.x;
    const int lane = tid & 63;
    const int wave = tid >> 6;            // 0..3
    const int nt   = blockIdx.x;          // 0..47
    const int mt   = blockIdx.y;          // 0..31
    const int g    = nt >> 3;             // gate 0..5
    const int hc0  = (nt & 7) * 128;      // h-col band
    const int m0   = mt * 128;
    const int wm   = (wave & 1) * 64;
    const int wn   = (wave >> 1) * 64;
    const int frow = lane & 15;
    const int fk   = (lane >> 4) * 8;
    const int colid = lane & 15;
    const int rbase = (lane >> 4) * 4;
    const int srow = lane >> 3;           // 0..7
    const int sc   = lane & 7;
    const int ssw  = ((sc ^ srow) << 3);  // XOR-swizzled source col (B staging)

    const unsigned short* Ax = xb + (size_t)m0 * K_DIM;
    const unsigned short* Ah = hb + (size_t)m0 * K_DIM;
    const unsigned short* Bw = Wb + ((size_t)g * H_DIM + hc0) * K_DIM;
    const unsigned short* Bu = Ub + ((size_t)g * H_DIM + hc0) * K_DIM;

    f32x4 acc[4][4];
#pragma unroll
    for (int ni = 0; ni < 4; ++ni) {
        float bv = b_all[g * H_DIM + hc0 + wn + ni * 16 + colid];
#pragma unroll
        for (int mi = 0; mi < 4; ++mi) acc[mi][ni] = (f32x4){bv, bv, bv, bv};
    }

    auto kloop = [&](const unsigned short* A, const unsigned short* B) {
        // per-lane A base: folds row (wm+frow) and k-phase fk
        const unsigned short* Ab = A + (size_t)(wm + frow) * K_DIM + fk;
        for (int k0 = 0; k0 < K_DIM; k0 += 64) {
            __syncthreads();              // protect lB from previous readers
#pragma unroll
            for (int q = 0; q < 4; ++q) {
                int c = wave * 4 + q;     // chunk 0..15 (8 rows each)
                int r = c * 8 + srow;
                GLDS(B + (size_t)r * K_DIM + k0 + ssw, &lB[c * 512]);
            }
            // A fragments direct from global (issued before the drain barrier)
            bf16x8 af[2][4];
#pragma unroll
            for (int s = 0; s < 2; ++s)
#pragma unroll
                for (int mi = 0; mi < 4; ++mi)
                    af[s][mi] = *(const bf16x8*)&Ab[(size_t)(mi * 16) * K_DIM + k0 + s * 32];
            __syncthreads();              // drains GLDS (and af loads)
#pragma unroll
            for (int s = 0; s < 2; ++s) {
                const int co = (((s * 4 + (lane >> 4)) ^ (lane & 7)) << 3);
                bf16x8 bf[4];
#pragma unroll
                for (int i = 0; i < 4; ++i)
                    bf[i] = *(const bf16x8*)&lB[(wn + i * 16 + frow) * 64 + co];
#pragma unroll
                for (int mi = 0; mi < 4; ++mi)
#pragma unroll
                    for (int ni = 0; ni < 4; ++ni)
                        acc[mi][ni] = __builtin_amdgcn_mfma_f32_16x16x32_bf16(
                            af[s][mi], bf[ni], acc[mi][ni], 0, 0, 0);
            }
        }
    };

    auto store_plane = [&](int p) {
        unsigned short* zp = z + (size_t)p * ZPL;
#pragma unroll
        for (int mi = 0; mi < 4; ++mi)
#pragma unroll
            for (int ni = 0; ni < 4; ++ni)
#pragma unroll
                for (int r = 0; r < 4; ++r) {
                    int row = m0 + wm + mi * 16 + rbase + r;
                    int cc  = hc0 + wn + ni * 16 + colid;
                    zp[(size_t)row * H_DIM + cc] = f2bf(acc[mi][ni][r]);
                }
    };

    kloop(Ax, Bw);                         // x @ W_g^T
    if (g == 4) {
        store_plane(5);                    // wx4 (+b4)
#pragma unroll
        for (int mi = 0; mi < 4; ++mi)
#pragma unroll
            for (int ni = 0; ni < 4; ++ni) acc[mi][ni] = (f32x4){0.f, 0.f, 0.f, 0.f};
    }
    kloop(Ah, Bu);                         // (+) h @ U_g^T
    store_plane(g == 4 ? 6 : (g == 5 ? 4 : g));
}

// ----------------------------------------------------------------- combine ---
__global__ __launch_bounds__(256) void combine(const unsigned short* __restrict__ z,
                                               const float* __restrict__ c_prev,
                                               float* __restrict__ out)
{
    const size_t e = ((size_t)blockIdx.x * 256 + threadIdx.x) * 8;
    u16x8 z0 = *(const u16x8*)&z[0 * ZPL + e];
    u16x8 z1 = *(const u16x8*)&z[1 * ZPL + e];
    u16x8 z2 = *(const u16x8*)&z[2 * ZPL + e];
    u16x8 z3 = *(const u16x8*)&z[3 * ZPL + e];
    u16x8 z4 = *(const u16x8*)&z[4 * ZPL + e];
    u16x8 z5 = *(const u16x8*)&z[5 * ZPL + e];
    u16x8 z6 = *(const u16x8*)&z[6 * ZPL + e];
    float hv[8], cv[8];
#pragma unroll
    for (int j = 0; j < 8; ++j) {
        float iv = sigm(bf2f(z0[j]));
        float fv = sigm(bf2f(z1[j]));
        float ov = sigm(bf2f(z2[j]));
        float gv = tanh_fast(bf2f(z3[j]));
        float av = sigm(bf2f(z4[j]));
        float mv = bf2f(z5[j]) * bf2f(z6[j]);
        float cp = c_prev[e + j];
        float cn = fv * cp + iv * gv + av * mv;
        cv[j] = cn;
        hv[j] = ov * tanh_fast(cn);
    }
#pragma unroll
    for (int j = 0; j < 8; ++j) {
        out[e + j] = hv[j];
        out[(size_t)B_DIM * H_DIM + e + j] = cv[j];
    }
}

// ------------------------------------------ fallback 1 (round-5 fused main) ---
constexpr int BM = 128, BN = 64, BK = 64;
constexpr int NKB = K_DIM / BK;

__global__ __launch_bounds__(512, 4)
void xlstm_main(const unsigned short* __restrict__ xb,
                const unsigned short* __restrict__ hb,
                const unsigned short* __restrict__ Wb,
                const unsigned short* __restrict__ Ub,
                const float* __restrict__ b_all,
                const float* __restrict__ c_prev,
                float* __restrict__ out)
{
    __shared__ unsigned short lA [2][BM * BK];
    __shared__ unsigned short lB0[2][BN * BK];
    __shared__ unsigned short lB1[2][BN * BK];

    const int tid  = threadIdx.x;
    const int lane = tid & 63;
    const int wave = tid >> 6;
    const int bn   = blockIdx.x * BN;
    const int bm   = blockIdx.y * BM;
    const int wm   = (wave & 3) * 32;
    const int wn   = (wave >> 2) * 32;
    const int frow = lane & 15;
    const int col  = lane & 15;
    const int rbase = (lane >> 4) * 4;
    const int srow = lane >> 3;
    const int sc   = lane & 7;
    const int scol_sw = ((sc ^ srow) << 3);

    const unsigned short* Ax = xb + (size_t)bm * K_DIM;
    const unsigned short* Ah = hb + (size_t)bm * K_DIM;

    f32x4 accA[2][2], accB[2][2], s1[2][2], s2[2][2], sm[2][2];

    auto issue = [&](const unsigned short* Abase, const unsigned short* B0,
                     const unsigned short* B1, int k0, int buf) {
#pragma unroll
        for (int q = 0; q < 2; ++q) {
            int c = wave + q * 8;
            int r = c * 8 + srow;
            GLDS(Abase + (size_t)r * K_DIM + k0 + scol_sw, &lA[buf][c * 512]);
        }
        {
            int r = wave * 8 + srow;
            GLDS(B0 + (size_t)r * K_DIM + k0 + scol_sw, &lB0[buf][wave * 512]);
            GLDS(B1 + (size_t)r * K_DIM + k0 + scol_sw, &lB1[buf][wave * 512]);
        }
    };

    auto mmstep = [&](int buf) {
#pragma unroll
        for (int s = 0; s < 2; ++s) {
            const int co = (((s * 4 + (lane >> 4)) ^ (lane & 7)) << 3);
            bf16x8 a0  = *(const bf16x8*)&lA [buf][(wm      + frow) * BK + co];
            bf16x8 a1  = *(const bf16x8*)&lA [buf][(wm + 16 + frow) * BK + co];
            bf16x8 b00 = *(const bf16x8*)&lB0[buf][(wn      + frow) * BK + co];
            bf16x8 b01 = *(const bf16x8*)&lB0[buf][(wn + 16 + frow) * BK + co];
            bf16x8 b10 = *(const bf16x8*)&lB1[buf][(wn      + frow) * BK + co];
            bf16x8 b11 = *(const bf16x8*)&lB1[buf][(wn + 16 + frow) * BK + co];
            accA[0][0] = __builtin_amdgcn_mfma_f32_16x16x32_bf16(a0, b00, accA[0][0], 0, 0, 0);
            accA[0][1] = __builtin_amdgcn_mfma_f32_16x16x32_bf16(a0, b01, accA[0][1], 0, 0, 0);
            accA[1][0] = __builtin_amdgcn_mfma_f32_16x16x32_bf16(a1, b00, accA[1][0], 0, 0, 0);
            accA[1][1] = __builtin_amdgcn_mfma_f32_16x16x32_bf16(a1, b01, accA[1][1], 0, 0, 0);
            accB[0][0] = __builtin_amdgcn_mfma_f32_16x16x32_bf16(a0, b10, accB[0][0], 0, 0, 0);
            accB[0][1] = __builtin_amdgcn_mfma_f32_16x16x32_bf16(a0, b11, accB[0][1], 0, 0, 0);
            accB[1][0] = __builtin_amdgcn_mfma_f32_16x16x32_bf16(a1, b10, accB[1][0], 0, 0, 0);
            accB[1][1] = __builtin_amdgcn_mfma_f32_16x16x32_bf16(a1, b11, accB[1][1], 0, 0, 0);
        }
    };

    auto stage = [&](const unsigned short* Abase, const unsigned short* B0,
                     const unsigned short* B1) {
        __syncthreads();
        issue(Abase, B0, B1, 0, 0);
        int cur = 0;
        for (int k = 0; k < NKB; ++k) {
            __syncthreads();
            if (k + 1 < NKB) issue(Abase, B0, B1, (k + 1) * BK, cur ^ 1);
            mmstep(cur);
            cur ^= 1;
        }
    };

#define WG(g) (Wb + (size_t)(g) * H_DIM * K_DIM + (size_t)bn * K_DIM)
#define UG(g) (Ub + (size_t)(g) * H_DIM * H_DIM + (size_t)bn * H_DIM)
#define SET_BIAS(acc, g) do {                                                   \
        float bv0 = b_all[(g) * H_DIM + bn + wn + col];                         \
        float bv1 = b_all[(g) * H_DIM + bn + wn + 16 + col];                    \
        _Pragma("unroll") for (int mi = 0; mi < 2; ++mi) {                      \
            acc[mi][0] = (f32x4){bv0, bv0, bv0, bv0};                           \
            acc[mi][1] = (f32x4){bv1, bv1, bv1, bv1};                           \
        }                                                                       \
    } while (0)

    SET_BIAS(accA, 4); SET_BIAS(accB, 5);
    stage(Ax, WG(4), WG(5));
#pragma unroll
    for (int mi = 0; mi < 2; ++mi)
#pragma unroll
        for (int ni = 0; ni < 2; ++ni) { sm[mi][ni] = accA[mi][ni]; accA[mi][ni] = (f32x4){0,0,0,0}; }
    stage(Ah, UG(4), UG(5));
#pragma unroll
    for (int mi = 0; mi < 2; ++mi)
#pragma unroll
        for (int ni = 0; ni < 2; ++ni)
#pragma unroll
            for (int r = 0; r < 4; ++r)
                s1[mi][ni][r] = sigm(accB[mi][ni][r]) * (sm[mi][ni][r] * accA[mi][ni][r]);

    SET_BIAS(accA, 1); SET_BIAS(accB, 0);
    stage(Ax, WG(1), WG(0));
    stage(Ah, UG(1), UG(0));
#pragma unroll
    for (int mi = 0; mi < 2; ++mi)
#pragma unroll
        for (int ni = 0; ni < 2; ++ni)
#pragma unroll
            for (int r = 0; r < 4; ++r) {
                int rg = bm + wm + mi * 16 + rbase + r;
                int cg = bn + wn + ni * 16 + col;
                float cp = c_prev[(size_t)rg * H_DIM + cg];
                s2[mi][ni][r] = sigm(accA[mi][ni][r]) * cp + s1[mi][ni][r];
                s1[mi][ni][r] = sigm(accB[mi][ni][r]);
            }

    SET_BIAS(accA, 3); SET_BIAS(accB, 2);
    stage(Ax, WG(3), WG(2));
    stage(Ah, UG(3), UG(2));
#pragma unroll
    for (int mi = 0; mi < 2; ++mi)
#pragma unroll
        for (int ni = 0; ni < 2; ++ni)
#pragma unroll
            for (int r = 0; r < 4; ++r) {
                int rg = bm + wm + mi * 16 + rbase + r;
                int cg = bn + wn + ni * 16 + col;
                float cn = s2[mi][ni][r] + s1[mi][ni][r] * tanh_fast(accA[mi][ni][r]);
                float hv = sigm(accB[mi][ni][r]) * tanh_fast(cn);
                out[(size_t)rg * H_DIM + cg] = hv;
                out[(size_t)B_DIM * H_DIM + (size_t)rg * H_DIM + cg] = cn;
            }
#undef WG
#undef UG
#undef SET_BIAS
}

// ------------------------------------------- fallback 2 (round-2, fp32 in) ---
constexpr int FBM = 128, FBN = 128, FBK = 64;
constexpr int FLDS = FBK + 8;

__device__ __forceinline__ void f_mm_pass(const float* __restrict__ Ag,
                                          const float* __restrict__ Bg,
                                          unsigned short* lA, unsigned short* lB,
                                          int st_r, int st_c, int wm, int wn, int frow, int fk,
                                          f32x4 acc[4][2])
{
    for (int k0 = 0; k0 < K_DIM; k0 += FBK) {
#pragma unroll
        for (int q = 0; q < 4; ++q) {
            const int r = st_r + 32 * q;
            f32x4 av = *(const f32x4*)&Ag[(size_t)r * K_DIM + k0 + st_c];
            f32x4 bv = *(const f32x4*)&Bg[(size_t)r * K_DIM + k0 + st_c];
            u16x4 ap = { f2bf(av[0]), f2bf(av[1]), f2bf(av[2]), f2bf(av[3]) };
            u16x4 bp = { f2bf(bv[0]), f2bf(bv[1]), f2bf(bv[2]), f2bf(bv[3]) };
            *(u16x4*)&lA[r * FLDS + st_c] = ap;
            *(u16x4*)&lB[r * FLDS + st_c] = bp;
        }
        __syncthreads();
#pragma unroll
        for (int kk = 0; kk < FBK; kk += 32) {
            bf16x8 bfr0 = *(const bf16x8*)&lB[(wn      + frow) * FLDS + kk + fk];
            bf16x8 bfr1 = *(const bf16x8*)&lB[(wn + 16 + frow) * FLDS + kk + fk];
#pragma unroll
            for (int mi = 0; mi < 4; ++mi) {
                bf16x8 afr = *(const bf16x8*)&lA[(wm + mi * 16 + frow) * FLDS + kk + fk];
                acc[mi][0] = __builtin_amdgcn_mfma_f32_16x16x32_bf16(afr, bfr0, acc[mi][0], 0, 0, 0);
                acc[mi][1] = __builtin_amdgcn_mfma_f32_16x16x32_bf16(afr, bfr1, acc[mi][1], 0, 0, 0);
            }
        }
        __syncthreads();
    }
}

extern "C" __global__ __launch_bounds__(512, 2)
void xlstm_fused_f32(const float* __restrict__ x, const float* __restrict__ h_prev,
                     const float* __restrict__ c_prev, const float* __restrict__ W_all,
                     const float* __restrict__ b_all, const float* __restrict__ U_all,
                     float* __restrict__ out)
{
    __shared__ unsigned short lA[FBM * FLDS];
    __shared__ unsigned short lB[FBN * FLDS];
    const int tid = threadIdx.x;
    const int bm = blockIdx.y * FBM, bn = blockIdx.x * FBN;
    const int st_r = tid >> 4, st_c = (tid & 15) * 4;
    const int lane = tid & 63, wave = tid >> 6;
    const int wm = (wave & 1) * 64, wn = (wave >> 1) * 32;
    const int frow = lane & 15, fk = (lane >> 4) * 8;
    const int col = lane & 15, rbase = (lane >> 4) * 4;
    const float* Axt = x + (size_t)bm * K_DIM;
    const float* Aht = h_prev + (size_t)bm * K_DIM;
    f32x4 acc[4][2], s1[4][2], s2[4][2];
#define WGf(g) (W_all + (size_t)(g) * H_DIM * K_DIM + (size_t)bn * K_DIM)
#define UGf(g) (U_all + (size_t)(g) * H_DIM * H_DIM + (size_t)bn * H_DIM)
#define SET_BIASf(g) do {                                                       \
        float bv0 = b_all[(g) * H_DIM + bn + wn + col];                         \
        float bv1 = b_all[(g) * H_DIM + bn + wn + 16 + col];                    \
        _Pragma("unroll") for (int mi = 0; mi < 4; ++mi) {                      \
            acc[mi][0] = (f32x4){bv0, bv0, bv0, bv0};                           \
            acc[mi][1] = (f32x4){bv1, bv1, bv1, bv1};                           \
        }                                                                       \
    } while (0)
#define RUN_GATEf(g) do { SET_BIASf(g);                                         \
        f_mm_pass(Axt, WGf(g), lA, lB, st_r, st_c, wm, wn, frow, fk, acc);      \
        f_mm_pass(Aht, UGf(g), lA, lB, st_r, st_c, wm, wn, frow, fk, acc); } while (0)
    SET_BIASf(4);
    f_mm_pass(Axt, WGf(4), lA, lB, st_r, st_c, wm, wn, frow, fk, acc);
    for (int mi = 0; mi < 4; ++mi) for (int ni = 0; ni < 2; ++ni) s1[mi][ni] = acc[mi][ni];
    for (int mi = 0; mi < 4; ++mi) for (int ni = 0; ni < 2; ++ni) acc[mi][ni] = (f32x4){0,0,0,0};
    f_mm_pass(Aht, UGf(4), lA, lB, st_r, st_c, wm, wn, frow, fk, acc);
    for (int mi = 0; mi < 4; ++mi) for (int ni = 0; ni < 2; ++ni) s1[mi][ni] *= acc[mi][ni];
    RUN_GATEf(5);
    for (int mi = 0; mi < 4; ++mi) for (int ni = 0; ni < 2; ++ni)
        for (int r = 0; r < 4; ++r) s1[mi][ni][r] = sigm(acc[mi][ni][r]) * s1[mi][ni][r];
    RUN_GATEf(1);
    for (int mi = 0; mi < 4; ++mi) for (int ni = 0; ni < 2; ++ni)
        for (int r = 0; r < 4; ++r) {
            int rg = bm + wm + mi * 16 + rbase + r, cg = bn + wn + ni * 16 + col;
            s2[mi][ni][r] = sigm(acc[mi][ni][r]) * c_prev[(size_t)rg * H_DIM + cg] + s1[mi][ni][r];
        }
    RUN_GATEf(0);
    for (int mi = 0; mi < 4; ++mi) for (int ni = 0; ni < 2; ++ni)
        for (int r = 0; r < 4; ++r) s1[mi][ni][r] = sigm(acc[mi][ni][r]);
    RUN_GATEf(3);
    for (int mi = 0; mi < 4; ++mi) for (int ni = 0; ni < 2; ++ni)
        for (int r = 0; r < 4; ++r) s2[mi][ni][r] += s1[mi][ni][r] * tanh_fast(acc[mi][ni][r]);
    RUN_GATEf(2);
    for (int mi = 0; mi < 4; ++mi) for (int ni = 0; ni < 2; ++ni)
        for (int r = 0; r < 4; ++r) {
            int rg = bm + wm + mi * 16 + rbase + r, cg = bn + wn + ni * 16 + col;
            float cn = s2[mi][ni][r];
            out[(size_t)rg * H_DIM + cg] = sigm(acc[mi][ni][r]) * tanh_fast(cn);
            out[(size_t)B_DIM * H_DIM + (size_t)rg * H_DIM + cg] = cn;
        }
#undef WGf
#undef UGf
#undef SET_BIASf
#undef RUN_GATEf
}

// ------------------------------------------------------------------ launch ---
extern "C" void kernel_launch(void* const* d_in, const int* in_sizes, int n_in,
                              void* d_out, int out_size, void* d_ws, size_t ws_size,
                              hipStream_t stream)
{
    (void)in_sizes; (void)n_in; (void)out_size;
    const float* x      = (const float*)d_in[0];
    const float* h_prev = (const float*)d_in[1];
    const float* c_prev = (const float*)d_in[2];
    const float* W_all  = (const float*)d_in[3];
    const float* b_all  = (const float*)d_in[4];
    const float* U_all  = (const float*)d_in[5];
    float* out = (float*)d_out;

    const size_t need_z  = (WS_Z + 7 * ZPL) * 2ull;
    const size_t need_r5 = WS_Z * 2ull;
    unsigned short* wsb = (unsigned short*)d_ws;

    if (ws_size >= need_z) {
        hipLaunchKernelGGL(cvt_all, dim3(2560), dim3(256), 0, stream,
                           x, h_prev, W_all, U_all, wsb);
        hipLaunchKernelGGL(gemm_z, dim3(48, 32), dim3(256), 0, stream,
                           wsb + WS_X, wsb + WS_H, wsb + WS_W, wsb + WS_U,
                           b_all, wsb + WS_Z);
        hipLaunchKernelGGL(combine, dim3(2048), dim3(256), 0, stream,
                           wsb + WS_Z, c_prev, out);
    } else if (ws_size >= need_r5) {
        hipLaunchKernelGGL(cvt_all, dim3(2560), dim3(256), 0, stream,
                           x, h_prev, W_all, U_all, wsb);
        hipLaunchKernelGGL(xlstm_main, dim3(H_DIM / BN, B_DIM / BM), dim3(512), 0, stream,
                           wsb + WS_X, wsb + WS_H, wsb + WS_W, wsb + WS_U,
                           b_all, c_prev, out);
    } else {
        hipLaunchKernelGGL(xlstm_fused_f32, dim3(H_DIM / FBN, B_DIM / FBM), dim3(512), 0, stream,
                           x, h_prev, c_prev, W_all, b_all, U_all, out);
    }
}